// Round 8
// baseline (79.275 us; speedup 1.0000x reference)
//
#include <hip/hip_runtime.h>
#include <hip/hip_bf16.h>
#include <math.h>

// Problem constants (fixed by reference setup_inputs)
constexpr int B = 2;
constexpr int N = 4096;   // pred points per batch
constexpr int M = 4096;   // target points per batch
constexpr int L = 512;    // latent dim

constexpr float KL_W = 0.001f;
constexpr float Q_W  = 0.1f;

// pairmin tiling
constexpr int THREADS = 256;
constexpr int QPT     = 4;               // queries per thread (strided by THREADS)
constexpr int QC      = THREADS * QPT;   // 1024 queries per block
constexpr int DT      = 256;             // data-tile points (4 KB LDS)
constexpr int GX      = N / QC;          // 4
constexpr int GY      = M / DT;          // 16 partial-min slices
constexpr int GZ      = 3 * B;           // 6  -> 384 blocks, 6 waves/CU

// ws layout:
//   [0)        float  partial[GY][GZ][N]   1.5 MB  (every slot written once)
//   [1572864)  double blocksums[24][2]     384 B
constexpr size_t OFF_PARTIAL = 0;
constexpr size_t OFF_BSUMS   = (size_t)GY * GZ * N * 4;

__global__ __launch_bounds__(THREADS) void mgl_pairmin_kernel(
    const float* __restrict__ pred, const float* __restrict__ target,
    float* __restrict__ partial)
{
    __shared__ float4 tile[DT];

    const int z   = blockIdx.z;     // 0..5
    const int dir = z >> 1;
    const int b   = z & 1;

    const float* qb; const float* db;
    if (dir == 0)      { qb = pred   + b * N * 3; db = target + b * M * 3; }
    else if (dir == 1) { qb = target + b * M * 3; db = pred   + b * N * 3; }
    else               { qb = pred   + b * N * 3; db = pred   + b * N * 3; }

    const int q0 = blockIdx.x * QC;
    const int d0 = blockIdx.y * DT;

    // stage data tile: compute |t|^2 during staging (once per point, reused by 1024 queries)
    {
        const float* p = db + (size_t)(d0 + threadIdx.x) * 3;
        float x = p[0], y = p[1], zz = p[2];
        tile[threadIdx.x] = make_float4(x, y, zz, fmaf(x, x, fmaf(y, y, zz * zz)));
    }

    // QPT strided queries per thread (12 B/lane spans, coalesced)
    int   qi[QPT];
    float ax[QPT], ay[QPT], az[QPT], qw[QPT], m[QPT];
    #pragma unroll
    for (int k = 0; k < QPT; ++k) {
        qi[k] = q0 + threadIdx.x + k * THREADS;
        float x = qb[qi[k] * 3 + 0], y = qb[qi[k] * 3 + 1], zz = qb[qi[k] * 3 + 2];
        qw[k] = fmaf(x, x, fmaf(y, y, zz * zz));
        ax[k] = -2.0f * x; ay[k] = -2.0f * y; az[k] = -2.0f * zz;
        m[k]  = 3.402823466e+38f;
    }

    __syncthreads();

    // diagonal can only appear in dir-2 blocks whose d-tile overlaps their q-range
    const bool diag = (dir == 2) && (d0 < q0 + QC) && (d0 + DT > q0);

    if (!diag) {
        #pragma unroll 8
        for (int j = 0; j < DT; ++j) {
            float4 t = tile[j];   // wave-uniform address: LDS broadcast, conflict-free
            #pragma unroll
            for (int k = 0; k < QPT; ++k) {
                float v = fmaf(ax[k], t.x, fmaf(ay[k], t.y, fmaf(az[k], t.z, t.w)));
                m[k] = fminf(m[k], v);
            }
        }
    } else {
        #pragma unroll 8
        for (int j = 0; j < DT; ++j) {
            float4 t = tile[j];
            const int dj = d0 + j;
            #pragma unroll
            for (int k = 0; k < QPT; ++k) {
                float v = fmaf(ax[k], t.x, fmaf(ay[k], t.y, fmaf(az[k], t.z, t.w)));
                v = (dj == qi[k]) ? 3.402823466e+38f : v;   // exclude diagonal (ref masks +1e6)
                m[k] = fminf(m[k], v);
            }
        }
    }

    // add |q|^2 (constant per query, commutes with min); clamp tiny negative from cancellation
    // plain coalesced stores; every (gy,z,qi) slot written exactly once -> no init, no atomics
    float* slice = partial + ((size_t)blockIdx.y * GZ + z) * N;
    #pragma unroll
    for (int k = 0; k < QPT; ++k)
        slice[qi[k]] = fmaxf(m[k] + qw[k], 0.0f);
}

// 24 blocks x 256 threads = 6144 threads = one (z, q4) task each.
// Block b handles z = b>>2, queries [ (b&3)*1024 , +1024 ) grouped by 4.
__global__ __launch_bounds__(256) void mgl_reduce_kernel(
    const float* __restrict__ partial, double* __restrict__ blocksums)
{
    const int tid = threadIdx.x;
    const int bid = blockIdx.x;            // 0..23
    const int z   = bid >> 2;              // 0..5
    const int q4  = ((bid & 3) * 256 + tid) * 4;

    const float4* p = (const float4*)(partial + (size_t)z * N + q4);
    float4 m = p[0];
    #pragma unroll
    for (int gy = 1; gy < GY; ++gy) {
        float4 v = p[(size_t)gy * (GZ * N / 4)];
        m.x = fminf(m.x, v.x); m.y = fminf(m.y, v.y);
        m.z = fminf(m.z, v.z); m.w = fminf(m.w, v.w);
    }

    double s  = (double)m.x + (double)m.y + (double)m.z + (double)m.w;
    double ss = (double)m.x * m.x + (double)m.y * m.y
              + (double)m.z * m.z + (double)m.w * m.w;

    // wave64 shuffle reduce, then cross-wave via LDS
    #pragma unroll
    for (int off = 32; off > 0; off >>= 1) {
        s  += __shfl_down(s,  off, 64);
        ss += __shfl_down(ss, off, 64);
    }
    __shared__ double wred[4][2];
    const int wid  = tid >> 6;
    const int lane = tid & 63;
    if (lane == 0) { wred[wid][0] = s; wred[wid][1] = ss; }
    __syncthreads();
    if (tid == 0) {
        double ts  = wred[0][0] + wred[1][0] + wred[2][0] + wred[3][0];
        double tss = wred[0][1] + wred[1][1] + wred[2][1] + wred[3][1];
        blocksums[bid * 2 + 0] = ts;
        blocksums[bid * 2 + 1] = tss;
    }
}

__global__ __launch_bounds__(256) void mgl_final_kernel(
    const double* __restrict__ blocksums, const float* __restrict__ mu,
    const float* __restrict__ logvar, float* __restrict__ out)
{
    const int tid = threadIdx.x;

    // KL over B*L = 1024 elements, 4 per thread
    double skl = 0.0;
    #pragma unroll
    for (int k = 0; k < 4; ++k) {
        int i = tid * 4 + k;
        double m  = (double)mu[i];
        double lv = (double)logvar[i];
        skl += 1.0 + lv - m * m - exp(lv);
    }
    #pragma unroll
    for (int off = 32; off > 0; off >>= 1)
        skl += __shfl_down(skl, off, 64);

    __shared__ double wkl[4];
    const int wid  = tid >> 6;
    const int lane = tid & 63;
    if (lane == 0) wkl[wid] = skl;
    __syncthreads();

    if (tid == 0) {
        double tkl = wkl[0] + wkl[1] + wkl[2] + wkl[3];

        double sPT[B] = {0.0, 0.0}, sTP[B] = {0.0, 0.0};
        double sPP[B] = {0.0, 0.0}, ssPP[B] = {0.0, 0.0};
        for (int bid = 0; bid < 24; ++bid) {
            const int z   = bid >> 2;
            const int dir = z >> 1;
            const int bb  = z & 1;
            double s  = blocksums[bid * 2 + 0];
            double ss = blocksums[bid * 2 + 1];
            if (dir == 0)      sPT[bb] += s;
            else if (dir == 1) sTP[bb] += s;
            else             { sPP[bb] += s; ssPP[bb] += ss; }
        }

        double cd = 0.0;
        #pragma unroll
        for (int bb = 0; bb < B; ++bb)
            cd += sPT[bb] / (double)N + sTP[bb] / (double)M;
        cd /= (double)B;

        double density = 0.0;
        #pragma unroll
        for (int bb = 0; bb < B; ++bb) {
            double s  = sPP[bb];
            double ss = ssPP[bb];
            double var = (ss - s * s / (double)N) / (double)(N - 1);
            density += sqrt(var > 0.0 ? var : 0.0);
        }
        density /= (double)B;

        double kl = -0.5 * tkl / (double)(B * L);

        double total = cd + (double)KL_W * kl + (double)Q_W * density;
        out[0] = (float)total;
        out[1] = (float)cd;
        out[2] = (float)kl;
        out[3] = (float)density;
    }
}

extern "C" void kernel_launch(void* const* d_in, const int* in_sizes, int n_in,
                              void* d_out, int out_size, void* d_ws, size_t ws_size,
                              hipStream_t stream) {
    const float* pred   = (const float*)d_in[0];
    const float* target = (const float*)d_in[1];
    const float* mu     = (const float*)d_in[2];
    const float* logvar = (const float*)d_in[3];
    float* out = (float*)d_out;

    char* ws = (char*)d_ws;
    float*  partial   = (float*)(ws + OFF_PARTIAL);
    double* blocksums = (double*)(ws + OFF_BSUMS);

    mgl_pairmin_kernel<<<dim3(GX, GY, GZ), THREADS, 0, stream>>>(pred, target, partial);
    mgl_reduce_kernel<<<24, 256, 0, stream>>>(partial, blocksums);
    mgl_final_kernel<<<1, 256, 0, stream>>>(blocksums, mu, logvar, out);
}

// Round 9
// 75.060 us; speedup vs baseline: 1.0561x; 1.0561x over previous
//
#include <hip/hip_runtime.h>
#include <hip/hip_bf16.h>
#include <math.h>

// Problem constants (fixed by reference setup_inputs)
constexpr int B = 2;
constexpr int N = 4096;   // pred points per batch
constexpr int M = 4096;   // target points per batch
constexpr int L = 512;    // latent dim

constexpr float KL_W = 0.001f;
constexpr float Q_W  = 0.1f;

// pairmin tiling: QPT=4 halves broadcast ds_read per pair; DT=128 keeps the
// grid at 768 blocks = exactly 3 blocks/CU (R8 showed 384 blocks = imbalance).
constexpr int THREADS = 256;
constexpr int QPT     = 4;               // queries per thread (strided by THREADS)
constexpr int QC      = THREADS * QPT;   // 1024 queries per block
constexpr int DT      = 128;             // data-tile points (2 KB LDS)
constexpr int GX      = N / QC;          // 4
constexpr int GY      = M / DT;          // 32 partial-min slices
constexpr int GZ      = 3 * B;           // 6  -> 768 blocks, 3 blocks/CU balanced

// ws layout:
//   [0)        float  partial[GY][GZ][N]   3 MB  (every slot written once)
//   [3145728)  double blocksums[24][2]     384 B
constexpr size_t OFF_PARTIAL = 0;
constexpr size_t OFF_BSUMS   = (size_t)GY * GZ * N * 4;

__global__ __launch_bounds__(THREADS) void mgl_pairmin_kernel(
    const float* __restrict__ pred, const float* __restrict__ target,
    float* __restrict__ partial)
{
    __shared__ float4 tile[DT];

    const int z   = blockIdx.z;     // 0..5
    const int dir = z >> 1;
    const int b   = z & 1;

    const float* qb; const float* db;
    if (dir == 0)      { qb = pred   + b * N * 3; db = target + b * M * 3; }
    else if (dir == 1) { qb = target + b * M * 3; db = pred   + b * N * 3; }
    else               { qb = pred   + b * N * 3; db = pred   + b * N * 3; }

    const int q0 = blockIdx.x * QC;
    const int d0 = blockIdx.y * DT;

    // stage data tile: compute |t|^2 during staging (once per point, reused by 1024 queries)
    if (threadIdx.x < DT) {
        const float* p = db + (size_t)(d0 + threadIdx.x) * 3;
        float x = p[0], y = p[1], zz = p[2];
        tile[threadIdx.x] = make_float4(x, y, zz, fmaf(x, x, fmaf(y, y, zz * zz)));
    }

    // QPT strided queries per thread (coalesced 12 B/lane wave spans)
    int   qi[QPT];
    float ax[QPT], ay[QPT], az[QPT], qw[QPT], m[QPT];
    #pragma unroll
    for (int k = 0; k < QPT; ++k) {
        qi[k] = q0 + threadIdx.x + k * THREADS;
        float x = qb[qi[k] * 3 + 0], y = qb[qi[k] * 3 + 1], zz = qb[qi[k] * 3 + 2];
        qw[k] = fmaf(x, x, fmaf(y, y, zz * zz));
        ax[k] = -2.0f * x; ay[k] = -2.0f * y; az[k] = -2.0f * zz;
        m[k]  = 3.402823466e+38f;
    }

    __syncthreads();

    // diagonal can only appear in dir-2 blocks whose d-tile overlaps their q-range
    const bool diag = (dir == 2) && (d0 < q0 + QC) && (d0 + DT > q0);

    if (!diag) {
        #pragma unroll 8
        for (int j = 0; j < DT; ++j) {
            float4 t = tile[j];   // wave-uniform address: LDS broadcast, conflict-free
            #pragma unroll
            for (int k = 0; k < QPT; ++k) {
                float v = fmaf(ax[k], t.x, fmaf(ay[k], t.y, fmaf(az[k], t.z, t.w)));
                m[k] = fminf(m[k], v);
            }
        }
    } else {
        #pragma unroll 8
        for (int j = 0; j < DT; ++j) {
            float4 t = tile[j];
            const int dj = d0 + j;
            #pragma unroll
            for (int k = 0; k < QPT; ++k) {
                float v = fmaf(ax[k], t.x, fmaf(ay[k], t.y, fmaf(az[k], t.z, t.w)));
                v = (dj == qi[k]) ? 3.402823466e+38f : v;   // exclude diagonal (ref masks +1e6)
                m[k] = fminf(m[k], v);
            }
        }
    }

    // add |q|^2 (constant per query, commutes with min); clamp tiny negative from cancellation
    // plain coalesced stores; every (gy,z,qi) slot written exactly once -> no init, no atomics
    float* slice = partial + ((size_t)blockIdx.y * GZ + z) * N;
    #pragma unroll
    for (int k = 0; k < QPT; ++k)
        slice[qi[k]] = fmaxf(m[k] + qw[k], 0.0f);
}

// 24 blocks x 256 threads = 6144 threads = one (z, q4) task each.
// Block b handles z = b>>2, queries [ (b&3)*1024 , +1024 ) grouped by 4.
__global__ __launch_bounds__(256) void mgl_reduce_kernel(
    const float* __restrict__ partial, double* __restrict__ blocksums)
{
    const int tid = threadIdx.x;
    const int bid = blockIdx.x;            // 0..23
    const int z   = bid >> 2;              // 0..5
    const int q4  = ((bid & 3) * 256 + tid) * 4;

    const float4* p = (const float4*)(partial + (size_t)z * N + q4);
    float4 m = p[0];
    #pragma unroll
    for (int gy = 1; gy < GY; ++gy) {
        float4 v = p[(size_t)gy * (GZ * N / 4)];
        m.x = fminf(m.x, v.x); m.y = fminf(m.y, v.y);
        m.z = fminf(m.z, v.z); m.w = fminf(m.w, v.w);
    }

    double s  = (double)m.x + (double)m.y + (double)m.z + (double)m.w;
    double ss = (double)m.x * m.x + (double)m.y * m.y
              + (double)m.z * m.z + (double)m.w * m.w;

    // wave64 shuffle reduce, then cross-wave via LDS
    #pragma unroll
    for (int off = 32; off > 0; off >>= 1) {
        s  += __shfl_down(s,  off, 64);
        ss += __shfl_down(ss, off, 64);
    }
    __shared__ double wred[4][2];
    const int wid  = tid >> 6;
    const int lane = tid & 63;
    if (lane == 0) { wred[wid][0] = s; wred[wid][1] = ss; }
    __syncthreads();
    if (tid == 0) {
        double ts  = wred[0][0] + wred[1][0] + wred[2][0] + wred[3][0];
        double tss = wred[0][1] + wred[1][1] + wred[2][1] + wred[3][1];
        blocksums[bid * 2 + 0] = ts;
        blocksums[bid * 2 + 1] = tss;
    }
}

__global__ __launch_bounds__(256) void mgl_final_kernel(
    const double* __restrict__ blocksums, const float* __restrict__ mu,
    const float* __restrict__ logvar, float* __restrict__ out)
{
    const int tid = threadIdx.x;

    // KL over B*L = 1024 elements, 4 per thread
    double skl = 0.0;
    #pragma unroll
    for (int k = 0; k < 4; ++k) {
        int i = tid * 4 + k;
        double m  = (double)mu[i];
        double lv = (double)logvar[i];
        skl += 1.0 + lv - m * m - exp(lv);
    }
    #pragma unroll
    for (int off = 32; off > 0; off >>= 1)
        skl += __shfl_down(skl, off, 64);

    __shared__ double wkl[4];
    const int wid  = tid >> 6;
    const int lane = tid & 63;
    if (lane == 0) wkl[wid] = skl;
    __syncthreads();

    if (tid == 0) {
        double tkl = wkl[0] + wkl[1] + wkl[2] + wkl[3];

        double sPT[B] = {0.0, 0.0}, sTP[B] = {0.0, 0.0};
        double sPP[B] = {0.0, 0.0}, ssPP[B] = {0.0, 0.0};
        for (int bid = 0; bid < 24; ++bid) {
            const int z   = bid >> 2;
            const int dir = z >> 1;
            const int bb  = z & 1;
            double s  = blocksums[bid * 2 + 0];
            double ss = blocksums[bid * 2 + 1];
            if (dir == 0)      sPT[bb] += s;
            else if (dir == 1) sTP[bb] += s;
            else             { sPP[bb] += s; ssPP[bb] += ss; }
        }

        double cd = 0.0;
        #pragma unroll
        for (int bb = 0; bb < B; ++bb)
            cd += sPT[bb] / (double)N + sTP[bb] / (double)M;
        cd /= (double)B;

        double density = 0.0;
        #pragma unroll
        for (int bb = 0; bb < B; ++bb) {
            double s  = sPP[bb];
            double ss = ssPP[bb];
            double var = (ss - s * s / (double)N) / (double)(N - 1);
            density += sqrt(var > 0.0 ? var : 0.0);
        }
        density /= (double)B;

        double kl = -0.5 * tkl / (double)(B * L);

        double total = cd + (double)KL_W * kl + (double)Q_W * density;
        out[0] = (float)total;
        out[1] = (float)cd;
        out[2] = (float)kl;
        out[3] = (float)density;
    }
}

extern "C" void kernel_launch(void* const* d_in, const int* in_sizes, int n_in,
                              void* d_out, int out_size, void* d_ws, size_t ws_size,
                              hipStream_t stream) {
    const float* pred   = (const float*)d_in[0];
    const float* target = (const float*)d_in[1];
    const float* mu     = (const float*)d_in[2];
    const float* logvar = (const float*)d_in[3];
    float* out = (float*)d_out;

    char* ws = (char*)d_ws;
    float*  partial   = (float*)(ws + OFF_PARTIAL);
    double* blocksums = (double*)(ws + OFF_BSUMS);

    mgl_pairmin_kernel<<<dim3(GX, GY, GZ), THREADS, 0, stream>>>(pred, target, partial);
    mgl_reduce_kernel<<<24, 256, 0, stream>>>(partial, blocksums);
    mgl_final_kernel<<<1, 256, 0, stream>>>(blocksums, mu, logvar, out);
}